// Round 2
// baseline (142.906 us; speedup 1.0000x reference)
//
#include <hip/hip_runtime.h>
#include <hip/hip_fp16.h>

typedef unsigned short u16;
typedef unsigned int   u32;
typedef u32   u32x2  __attribute__((ext_vector_type(2)));
typedef short short8 __attribute__((ext_vector_type(8)));
typedef float f32x4  __attribute__((ext_vector_type(4)));
typedef _Float16 half8 __attribute__((ext_vector_type(8)));

#define BB   8
#define CINC 128
#define COUTC 256
#define HH   64
#define WWID 64
#define LL   4096          // H*W
#define KD   1152          // 9*128, GEMM K
#define LT   32            // l-tile per block
#define KP   1160          // padded LDS cols row stride (f16 elems)

__device__ __forceinline__ u16 f2h(float f) {
  return __half_as_ushort(__float2half(f));
}
__device__ __forceinline__ float h2f(u16 h) {
  return __half2float(__ushort_as_half(h));
}
__device__ __forceinline__ f32x4 mfma16(short8 a, short8 b, f32x4 c) {
  return __builtin_amdgcn_mfma_f32_16x16x32_f16(
      __builtin_bit_cast(half8, a), __builtin_bit_cast(half8, b), c, 0, 0, 0);
}

// ---------------- prep: x NCHW f32 -> NHWC f16 ----------------
__global__ __launch_bounds__(256) void prep_x(const float* __restrict__ x,
                                              u16* __restrict__ xh) {
  __shared__ float tile[CINC][65];
  int bid = blockIdx.x;
  int b = bid >> 6, h = bid & 63;
  int tid = threadIdx.x;
  // load: lane = w (coalesced)
  for (int i = 0; i < 32; ++i) {
    int c = (tid >> 6) + i * 4;
    int w = tid & 63;
    tile[c][w] = x[(((size_t)b * CINC + c) * HH + h) * WWID + w];
  }
  __syncthreads();
  // store: lane = c (contiguous in NHWC)
  u16* dst = xh + ((size_t)(b * HH + h) * WWID) * CINC;
  for (int j = 0; j < 32; ++j) {
    int c = tid & 127;
    int w = (tid >> 7) + 2 * j;
    dst[w * CINC + c] = f2h(tile[c][w]);
  }
}

// ---------------- prep: weights -> f16 [o][kk*128+c] ----------------
__global__ __launch_bounds__(256) void prep_w(const float* __restrict__ w_dc,
                                              const float* __restrict__ w_off,
                                              u16* __restrict__ Wl,
                                              u16* __restrict__ Wol) {
  int idx = blockIdx.x * 256 + threadIdx.x;
  if (idx < COUTC * KD) {
    int o = idx / KD, r = idx - o * KD;
    int kk = r >> 7, c = r & 127;
    Wl[o * KD + r] = f2h(w_dc[(o * CINC + c) * 9 + kk]);
  } else {
    int i2 = idx - COUTC * KD;       // 0 .. 32*1152-1
    int o = i2 / KD, r = i2 - o * KD;
    int kk = r >> 7, c = r & 127;
    Wol[o * KD + r] = (o < 18) ? f2h(w_off[(o * CINC + c) * 9 + kk]) : (u16)0;
  }
}

// ---------------- fused offset-conv + deformable conv ----------------
struct SM {
  u16   cols[LT][KP];   // 74240 B : K x L tile, stored [l][k] (k-minor)
  float off[LT][18];    //  2304 B : offset-conv output per l
  u32   tblA[288];      //  1152 B : packed (y0,x0) int16 per (kk,l)
  float tblF[288][2];   //  2304 B : (fy, fx) fp32 bilinear fractions
};                      // 80000 B total -> 2 blocks/CU

__global__ __launch_bounds__(256, 2) void deform_main(
    const u16* __restrict__ xh, const u16* __restrict__ Wl,
    const u16* __restrict__ Wol, const float* __restrict__ b_off,
    const float* __restrict__ b_dc, float* __restrict__ out) {
  __shared__ SM sm;
  int bid = blockIdx.x;
  int b   = bid >> 7;
  int ho  = (bid >> 1) & 63;
  int wo0 = (bid & 1) * LT;
  int tid = threadIdx.x;
  int lane = tid & 63;
  int wv  = tid >> 6;
  int ln15 = lane & 15;
  int kg  = lane >> 4;          // 0..3 k-group
  int grp = tid >> 5;           // 0..7 (32-lane task groups)
  int cl  = (tid & 31) * 4;     // channel base (4 channels per lane-task)

  const u16* xb = xh + (size_t)b * (HH * WWID * CINC);

  // ---- phase 1: im2col with reflect padding ----
  for (int it = 0; it < 36; ++it) {
    int T = grp + it * 8;             // 0..287
    int kk = T >> 5, lc = T & 31;
    int ki = kk / 3, kj = kk - ki * 3;
    int hr = ho + ki - 1;  hr = hr < 0 ? -hr : (hr > 63 ? 126 - hr : hr);
    int wr = wo0 + lc + kj - 1; wr = wr < 0 ? -wr : (wr > 63 ? 126 - wr : wr);
    u32x2 v = *(const u32x2*)(xb + ((hr * WWID + wr) * CINC + cl));
    *(u32x2*)&sm.cols[lc][kk * CINC + cl] = v;
  }
  __syncthreads();

  // ---- phase 1 MFMA: offset conv (M=32 padded from 18) ----
  {
    int mt = wv & 1, nt = wv >> 1;
    f32x4 acc = {0.f, 0.f, 0.f, 0.f};
    const u16* wrow = Wol + (mt * 16 + ln15) * KD + kg * 8;
    const u16* brow = &sm.cols[nt * 16 + ln15][kg * 8];
    for (int ks = 0; ks < 36; ++ks) {
      short8 af = *(const short8*)(wrow + ks * 32);
      short8 bf = *(const short8*)(brow + ks * 32);
      acc = mfma16(af, bf, acc);
    }
    int l = nt * 16 + ln15;
#pragma unroll
    for (int r = 0; r < 4; ++r) {
      int co = mt * 16 + kg * 4 + r;
      if (co < 18) sm.off[l][co] = acc[r] + b_off[co];
    }
  }
  __syncthreads();

  // ---- phase 1.5: sampling table per (kk, l) — 288 tasks, 256 threads ----
  for (int T = tid; T < 288; T += 256) {
    int kk = T >> 5, lc = T & 31;
    int ki = kk / 3, kj = kk - ki * 3;
    float py = sm.off[lc][2 * kk]     + (float)(ho + ki - 1);
    float px = sm.off[lc][2 * kk + 1] + (float)(wo0 + lc + kj - 1);
    float fy0 = floorf(py), fx0 = floorf(px);
    int y0 = (int)fy0, x0 = (int)fx0;
    sm.tblA[T] = (u32)(y0 & 0xffff) | ((u32)(x0 & 0xffff) << 16);
    sm.tblF[T][0] = py - fy0;
    sm.tblF[T][1] = px - fx0;
  }
  __syncthreads();

  // ---- phase 2: bilinear gather -> cols tile (zero-pad OOB) ----
  for (int it = 0; it < 36; ++it) {
    int T = grp + it * 8;
    int kk = T >> 5, lc = T & 31;
    u32 a = sm.tblA[T];
    int y0 = (int)(short)(a & 0xffffu);
    int x0 = (int)(short)(a >> 16);
    float fy = sm.tblF[T][0];
    float fx = sm.tblF[T][1];
    float w11 = fy * fx;
    float w10 = fy - w11, w01 = fx - w11, w00 = 1.f - fy - fx + w11;
    int y1 = y0 + 1, x1 = x0 + 1;
    float m00 = (y0 >= 0 && y0 < 64 && x0 >= 0 && x0 < 64) ? w00 : 0.f;
    float m01 = (y0 >= 0 && y0 < 64 && x1 >= 0 && x1 < 64) ? w01 : 0.f;
    float m10 = (y1 >= 0 && y1 < 64 && x0 >= 0 && x0 < 64) ? w10 : 0.f;
    float m11 = (y1 >= 0 && y1 < 64 && x1 >= 0 && x1 < 64) ? w11 : 0.f;
    int yc0 = min(max(y0, 0), 63), yc1 = min(max(y1, 0), 63);
    int xc0 = min(max(x0, 0), 63), xc1 = min(max(x1, 0), 63);
    u32x2 v00 = *(const u32x2*)(xb + ((yc0 * WWID + xc0) * CINC + cl));
    u32x2 v01 = *(const u32x2*)(xb + ((yc0 * WWID + xc1) * CINC + cl));
    u32x2 v10 = *(const u32x2*)(xb + ((yc1 * WWID + xc0) * CINC + cl));
    u32x2 v11 = *(const u32x2*)(xb + ((yc1 * WWID + xc1) * CINC + cl));
    float r0 = m00 * h2f((u16)(v00[0] & 0xffff)) + m01 * h2f((u16)(v01[0] & 0xffff))
             + m10 * h2f((u16)(v10[0] & 0xffff)) + m11 * h2f((u16)(v11[0] & 0xffff));
    float r1 = m00 * h2f((u16)(v00[0] >> 16)) + m01 * h2f((u16)(v01[0] >> 16))
             + m10 * h2f((u16)(v10[0] >> 16)) + m11 * h2f((u16)(v11[0] >> 16));
    float r2 = m00 * h2f((u16)(v00[1] & 0xffff)) + m01 * h2f((u16)(v01[1] & 0xffff))
             + m10 * h2f((u16)(v10[1] & 0xffff)) + m11 * h2f((u16)(v11[1] & 0xffff));
    float r3 = m00 * h2f((u16)(v00[1] >> 16)) + m01 * h2f((u16)(v01[1] >> 16))
             + m10 * h2f((u16)(v10[1] >> 16)) + m11 * h2f((u16)(v11[1] >> 16));
    u32x2 pv;
    pv[0] = (u32)f2h(r0) | ((u32)f2h(r1) << 16);
    pv[1] = (u32)f2h(r2) | ((u32)f2h(r3) << 16);
    *(u32x2*)&sm.cols[lc][kk * CINC + cl] = pv;
  }
  __syncthreads();

  // ---- phase 2 MFMA: 256 x 32 output tile, K = 1152 ----
  f32x4 acc[4][2];
#pragma unroll
  for (int m = 0; m < 4; ++m) {
    acc[m][0] = (f32x4){0.f, 0.f, 0.f, 0.f};
    acc[m][1] = (f32x4){0.f, 0.f, 0.f, 0.f};
  }
  int ob = wv * 64;
  const u16* wbase  = Wl + (size_t)(ob + ln15) * KD + kg * 8;
  const u16* bbase0 = &sm.cols[ln15][kg * 8];
  const u16* bbase1 = &sm.cols[16 + ln15][kg * 8];
  for (int ks = 0; ks < 36; ++ks) {
    short8 bf0 = *(const short8*)(bbase0 + ks * 32);
    short8 bf1 = *(const short8*)(bbase1 + ks * 32);
#pragma unroll
    for (int m = 0; m < 4; ++m) {
      short8 af = *(const short8*)(wbase + m * (16 * KD) + ks * 32);
      acc[m][0] = mfma16(af, bf0, acc[m][0]);
      acc[m][1] = mfma16(af, bf1, acc[m][1]);
    }
  }
  // epilogue: out[b][o][ho*64 + wo0 + l] = acc + b_dc[o]
#pragma unroll
  for (int m = 0; m < 4; ++m) {
#pragma unroll
    for (int r = 0; r < 4; ++r) {
      int o = ob + m * 16 + kg * 4 + r;
      float bias = b_dc[o];
      size_t base = ((size_t)(b * COUTC + o)) * LL + ho * WWID + wo0;
#pragma unroll
      for (int nt = 0; nt < 2; ++nt) {
        out[base + nt * 16 + ln15] = acc[m][nt][r] + bias;
      }
    }
  }
}

extern "C" void kernel_launch(void* const* d_in, const int* in_sizes, int n_in,
                              void* d_out, int out_size, void* d_ws, size_t ws_size,
                              hipStream_t stream) {
  const float* x     = (const float*)d_in[0];
  const float* w_off = (const float*)d_in[1];
  const float* b_off = (const float*)d_in[2];
  const float* w_dc  = (const float*)d_in[3];
  const float* b_dc  = (const float*)d_in[4];
  float* out = (float*)d_out;
  char* ws = (char*)d_ws;
  u16* xh  = (u16*)ws;                          // 8,388,608 B
  u16* Wl  = (u16*)(ws + 8388608);              //   589,824 B
  u16* Wol = (u16*)(ws + 8388608 + 589824);     //    73,728 B
  prep_x<<<dim3(512), dim3(256), 0, stream>>>(x, xh);
  prep_w<<<dim3(1296), dim3(256), 0, stream>>>(w_dc, w_off, Wl, Wol);
  deform_main<<<dim3(1024), dim3(256), 0, stream>>>(xh, Wl, Wol, b_off, b_dc, out);
}

// Round 3
// 73.999 us; speedup vs baseline: 1.9312x; 1.9312x over previous
//
#include <hip/hip_runtime.h>
#include <hip/hip_fp16.h>

typedef unsigned short u16;
typedef unsigned int   u32;
typedef u32   u32x2  __attribute__((ext_vector_type(2)));
typedef u32   u32x4  __attribute__((ext_vector_type(4)));
typedef short short8 __attribute__((ext_vector_type(8)));
typedef float f32x4  __attribute__((ext_vector_type(4)));
typedef _Float16 half8 __attribute__((ext_vector_type(8)));

__device__ __forceinline__ u16 f2h(float f) { return __half_as_ushort(__float2half(f)); }
__device__ __forceinline__ f32x4 mfma16(short8 a, short8 b, f32x4 c) {
  return __builtin_amdgcn_mfma_f32_16x16x32_f16(
      __builtin_bit_cast(half8, a), __builtin_bit_cast(half8, b), c, 0, 0, 0);
}
__device__ __forceinline__ __half2 h2cast(u32 u) { return __builtin_bit_cast(__half2, u); }

// ---------------- prep: x NCHW f32 -> NHWC f16 ----------------
__global__ __launch_bounds__(256) void prep_x(const float* __restrict__ x,
                                              u16* __restrict__ xh) {
  __shared__ float tile[128][65];
  int bid = blockIdx.x;
  int swz = (bid & 7) * 64 + (bid >> 3);      // XCD x -> batch x
  int b = swz >> 6, h = swz & 63;
  int tid = threadIdx.x;
  for (int i = 0; i < 32; ++i) {
    int c = (tid >> 6) + i * 4;
    int w = tid & 63;
    tile[c][w] = x[(((size_t)b * 128 + c) * 64 + h) * 64 + w];
  }
  __syncthreads();
  u16* dst = xh + ((size_t)(b * 64 + h) * 64) * 128;
  for (int j = 0; j < 32; ++j) {
    int c = tid & 127;
    int w = (tid >> 7) + 2 * j;
    dst[w * 128 + c] = f2h(tile[c][w]);
  }
}

// ------- prep: weights -> f16, MFMA-fragment order -------
// Wl2  idx = (((kk*16+mt)*4+ks)*64+lane)*8+e : o=mt*16+(lane&15), c=ks*32+(lane>>4)*8+e
// Wol2 idx = (((kk*2 +mt)*4+ks)*64+lane)*8+e : co (pad 32, zero >=18)
__global__ __launch_bounds__(256) void prep_w(const float* __restrict__ w_dc,
                                              const float* __restrict__ w_off,
                                              u16* __restrict__ Wl2,
                                              u16* __restrict__ Wol2) {
  int idx = blockIdx.x * 256 + threadIdx.x;   // 0..331775
  if (idx < 294912) {
    int e = idx & 7, lane = (idx >> 3) & 63, ks = (idx >> 9) & 3;
    int mt = (idx >> 11) & 15, kk = idx >> 15;
    int o = mt * 16 + (lane & 15), c = ks * 32 + (lane >> 4) * 8 + e;
    Wl2[idx] = f2h(w_dc[(o * 128 + c) * 9 + kk]);
  } else {
    int i2 = idx - 294912;                    // 0..36863
    int e = i2 & 7, lane = (i2 >> 3) & 63, ks = (i2 >> 9) & 3;
    int mt = (i2 >> 11) & 1, kk = i2 >> 12;
    int co = mt * 16 + (lane & 15), c = ks * 32 + (lane >> 4) * 8 + e;
    Wol2[i2] = (co < 18) ? f2h(w_off[(co * 128 + c) * 9 + kk]) : (u16)0;
  }
}

// ---------------- offset conv -> sampling table ----------------
__device__ __forceinline__ void make_entry(u32x4* __restrict__ tblG, int b, int kk,
                                           int ho, int wo, float offy, float offx) {
  int ki = kk / 3, kj = kk - ki * 3;
  float py = offy + (float)(ho + ki - 1);
  float px = offx + (float)(wo + kj - 1);
  float fy0 = floorf(py), fx0 = floorf(px);
  int y0 = (int)fy0, x0 = (int)fx0;
  float fy = py - fy0, fx = px - fx0;
  float w11 = fy * fx, w10 = fy - w11, w01 = fx - w11, w00 = 1.f - fy - fx + w11;
  bool iy0 = (y0 >= 0) & (y0 < 64), iy1 = (y0 >= -1) & (y0 < 63);
  bool ix0 = (x0 >= 0) & (x0 < 64), ix1 = (x0 >= -1) & (x0 < 63);
  int y0c = min(max(y0, 0), 63), x0c = min(max(x0, 0), 63);
  u32 addr00 = (u32)((y0c * 64 + x0c) * 128);
  u32 dx = (x0 >= 0 && x0 < 63) ? 128u : 0u;
  u32 dy = (y0 >= 0 && y0 < 63) ? 8192u : 0u;
  u32 wA = (u32)f2h((iy0 && ix0) ? w00 : 0.f) | ((u32)f2h((iy0 && ix1) ? w01 : 0.f) << 16);
  u32 wB = (u32)f2h((iy1 && ix0) ? w10 : 0.f) | ((u32)f2h((iy1 && ix1) ? w11 : 0.f) << 16);
  u32x4 ent; ent.x = addr00; ent.y = dx | (dy << 16); ent.z = wA; ent.w = wB;
  tblG[((size_t)(b * 9 + kk) << 12) + (ho << 6) + wo] = ent;
}

__global__ __launch_bounds__(256) void offset_k(const u16* __restrict__ xh,
                                                const u16* __restrict__ Wol2,
                                                const float* __restrict__ b_off,
                                                u32x4* __restrict__ tblG) {
  __shared__ u16 cols[2][64][128];
  int bid = blockIdx.x;
  int swz = (bid & 7) * 64 + (bid >> 3);
  int b = swz >> 6, ho = swz & 63;
  int tid = threadIdx.x, lane = tid & 63, wv = tid >> 6;
  int ln15 = lane & 15, kg = lane >> 4;
  const u16* xb = xh + (size_t)b * 524288;

  auto stage = [&](int kn, int dbuf) {
    int ki = kn / 3, kj = kn - ki * 3;
    int hr = ho + ki - 1; hr = hr < 0 ? -hr : (hr > 63 ? 126 - hr : hr);
#pragma unroll
    for (int i = 0; i < 8; ++i) {
      int t = tid + i * 256;
      int cl = (t & 31) * 4, l = t >> 5;
      int wr = l + kj - 1; wr = wr < 0 ? -wr : (wr > 63 ? 126 - wr : wr);
      u32x2 v = *(const u32x2*)(xb + (hr * 64 + wr) * 128 + cl);
      *(u32x2*)&cols[dbuf][l][cl ^ ((l & 7) << 3)] = v;
    }
  };

  f32x4 acc0 = {0.f, 0.f, 0.f, 0.f}, acc1 = {0.f, 0.f, 0.f, 0.f};
  int lq = wv * 16 + ln15;                 // this lane's l (column)

  stage(0, 0);
  __syncthreads();
  for (int kk = 0; kk < 9; ++kk) {
    int buf = kk & 1;
    if (kk < 8) stage(kk + 1, buf ^ 1);
    const u16* wb = Wol2 + (size_t)kk * 2 * 4 * 512;
#pragma unroll
    for (int ks = 0; ks < 4; ++ks) {
      short8 bfv = *(const short8*)&cols[buf][lq][(ks * 32 + kg * 8) ^ ((lq & 7) << 3)];
      short8 a0 = *(const short8*)(wb + (0 * 4 + ks) * 512 + lane * 8);
      short8 a1 = *(const short8*)(wb + (1 * 4 + ks) * 512 + lane * 8);
      acc0 = mfma16(a0, bfv, acc0);
      acc1 = mfma16(a1, bfv, acc1);
    }
    __syncthreads();
  }
  // epilogue: lane holds offset-channels co=kg*4+r (acc0), 16+kg*4+r (acc1), col l=lq
  int wo = lq;
  int kkA = kg * 2, kkB = kg * 2 + 1;
  make_entry(tblG, b, kkA, ho, wo, acc0[0] + b_off[2 * kkA], acc0[1] + b_off[2 * kkA + 1]);
  make_entry(tblG, b, kkB, ho, wo, acc0[2] + b_off[2 * kkB], acc0[3] + b_off[2 * kkB + 1]);
  if (kg == 0)
    make_entry(tblG, b, 8, ho, wo, acc1[0] + b_off[16], acc1[1] + b_off[17]);
}

// ---------------- main: gather || MFMA, kk-sliced double buffer ----------------
__global__ __launch_bounds__(512, 4) void deform_main(
    const u16* __restrict__ xh, const u16* __restrict__ Wl2,
    const u32x4* __restrict__ tblG, const float* __restrict__ b_dc,
    float* __restrict__ out) {
  __shared__ u16 cols[2][64][128];     // 32768 B
  __shared__ u32x4 tbl[576];           //  9216 B
  int bid = blockIdx.x;
  int swz = (bid & 7) * 64 + (bid >> 3);
  int b = swz >> 6, ho = swz & 63;
  int tid = threadIdx.x, lane = tid & 63, wv = tid >> 6;
  int ln15 = lane & 15, kg = lane >> 4;
  const u16* xb = xh + (size_t)b * 524288;

  // stage sampling table: 576 entries
  {
    size_t base = (size_t)b * 9 * 4096 + ho * 64;
    tbl[tid] = tblG[base + (tid >> 6) * 4096 + (tid & 63)];
    if (tid < 64) tbl[512 + tid] = tblG[base + 8 * 4096 + tid];
  }
  __syncthreads();

  auto gather = [&](int g, int dbuf) {
#pragma unroll
    for (int i = 0; i < 4; ++i) {
      int t = tid + i * 512;
      int cl = (t & 31) * 4, l = t >> 5;
      u32x4 e = tbl[g * 64 + l];
      const u16* p = xb + e.x + cl;
      u32 dxv = e.y & 0xffffu, dyv = e.y >> 16;
      u32x2 v00 = *(const u32x2*)p;
      u32x2 v01 = *(const u32x2*)(p + dxv);
      u32x2 v10 = *(const u32x2*)(p + dyv);
      u32x2 v11 = *(const u32x2*)(p + dyv + dxv);
      __half2 wA = h2cast(e.z), wB = h2cast(e.w);
      __half2 w00 = __half2half2(wA.x), w01 = __half2half2(wA.y);
      __half2 w10 = __half2half2(wB.x), w11 = __half2half2(wB.y);
      __half2 r0 = __hmul2(h2cast(v00[0]), w00);
      r0 = __hfma2(h2cast(v01[0]), w01, r0);
      r0 = __hfma2(h2cast(v10[0]), w10, r0);
      r0 = __hfma2(h2cast(v11[0]), w11, r0);
      __half2 r1 = __hmul2(h2cast(v00[1]), w00);
      r1 = __hfma2(h2cast(v01[1]), w01, r1);
      r1 = __hfma2(h2cast(v10[1]), w10, r1);
      r1 = __hfma2(h2cast(v11[1]), w11, r1);
      u32x2 pv;
      pv[0] = __builtin_bit_cast(u32, r0);
      pv[1] = __builtin_bit_cast(u32, r1);
      *(u32x2*)&cols[dbuf][l][cl ^ ((l & 7) << 3)] = pv;
    }
  };

  f32x4 acc[2][4];
#pragma unroll
  for (int m = 0; m < 2; ++m)
#pragma unroll
    for (int n = 0; n < 4; ++n) acc[m][n] = (f32x4){0.f, 0.f, 0.f, 0.f};

  gather(0, 0);
  __syncthreads();

  for (int kk = 0; kk < 9; ++kk) {
    int buf = kk & 1;
    if (kk < 8) gather(kk + 1, buf ^ 1);
    const u16* wbase = Wl2 + (size_t)((kk * 16 + wv * 2) * 4) * 512;
#pragma unroll
    for (int ks = 0; ks < 4; ++ks) {
      short8 a0 = *(const short8*)(wbase + ks * 512 + lane * 8);
      short8 a1 = *(const short8*)(wbase + (4 + ks) * 512 + lane * 8);
#pragma unroll
      for (int nt = 0; nt < 4; ++nt) {
        int l = nt * 16 + ln15;
        short8 bfv = *(const short8*)&cols[buf][l][(ks * 32 + kg * 8) ^ ((l & 7) << 3)];
        acc[0][nt] = mfma16(a0, bfv, acc[0][nt]);
        acc[1][nt] = mfma16(a1, bfv, acc[1][nt]);
      }
    }
    __syncthreads();
  }

  // epilogue
#pragma unroll
  for (int mt = 0; mt < 2; ++mt) {
#pragma unroll
    for (int r = 0; r < 4; ++r) {
      int o = wv * 32 + mt * 16 + kg * 4 + r;
      float bias = b_dc[o];
      size_t base = ((size_t)(b * 256 + o)) * 4096 + ho * 64;
#pragma unroll
      for (int nt = 0; nt < 4; ++nt) {
        out[base + nt * 16 + ln15] = acc[mt][nt][r] + bias;
      }
    }
  }
}

extern "C" void kernel_launch(void* const* d_in, const int* in_sizes, int n_in,
                              void* d_out, int out_size, void* d_ws, size_t ws_size,
                              hipStream_t stream) {
  const float* x     = (const float*)d_in[0];
  const float* w_off = (const float*)d_in[1];
  const float* b_off = (const float*)d_in[2];
  const float* w_dc  = (const float*)d_in[3];
  const float* b_dc  = (const float*)d_in[4];
  float* out = (float*)d_out;
  char* ws = (char*)d_ws;
  u16*   xh   = (u16*)ws;                                   // 8,388,608 B
  u16*   Wl2  = (u16*)(ws + 8388608);                       //   589,824 B
  u16*   Wol2 = (u16*)(ws + 8388608 + 589824);              //    73,728 B
  u32x4* tblG = (u32x4*)(ws + 9052160);                     // 4,718,592 B (tot 13.8 MB)
  prep_x  <<<dim3(512),  dim3(256), 0, stream>>>(x, xh);
  prep_w  <<<dim3(1296), dim3(256), 0, stream>>>(w_dc, w_off, Wl2, Wol2);
  offset_k<<<dim3(512),  dim3(256), 0, stream>>>(xh, Wol2, b_off, tblG);
  deform_main<<<dim3(512), dim3(512), 0, stream>>>(xh, Wl2, tblG, b_dc, out);
}

// Round 4
// 58.550 us; speedup vs baseline: 2.4408x; 1.2639x over previous
//
#include <hip/hip_runtime.h>
#include <hip/hip_fp16.h>

typedef unsigned short u16;
typedef unsigned int   u32;
typedef u32   u32x2  __attribute__((ext_vector_type(2)));
typedef u32   u32x4  __attribute__((ext_vector_type(4)));
typedef short short8 __attribute__((ext_vector_type(8)));
typedef float f32x4  __attribute__((ext_vector_type(4)));
typedef _Float16 half8 __attribute__((ext_vector_type(8)));

__device__ __forceinline__ u16 f2h(float f) { return __half_as_ushort(__float2half(f)); }
__device__ __forceinline__ f32x4 mfma16(short8 a, short8 b, f32x4 c) {
  return __builtin_amdgcn_mfma_f32_16x16x32_f16(
      __builtin_bit_cast(half8, a), __builtin_bit_cast(half8, b), c, 0, 0, 0);
}
__device__ __forceinline__ __half2 h2cast(u32 u) { return __builtin_bit_cast(__half2, u); }

// ---------------- fused prep: x NCHW f32 -> NHWC f16 ; weights -> MFMA order ----------------
__global__ __launch_bounds__(256) void prep_fused(const float* __restrict__ x,
                                                  const float* __restrict__ w_dc,
                                                  const float* __restrict__ w_off,
                                                  u16* __restrict__ xh,
                                                  u16* __restrict__ Wl2,
                                                  u16* __restrict__ Wol2) {
  int bid = blockIdx.x;
  int tid = threadIdx.x;
  if (bid < 512) {
    __shared__ float tile[128][65];
    int swz = (bid & 7) * 64 + (bid >> 3);
    int b = swz >> 6, h = swz & 63;
    for (int i = 0; i < 32; ++i) {
      int c = (tid >> 6) + i * 4;
      int w = tid & 63;
      tile[c][w] = x[(((size_t)b * 128 + c) * 64 + h) * 64 + w];
    }
    __syncthreads();
    u16* dst = xh + ((size_t)(b * 64 + h) * 64) * 128;
    for (int j = 0; j < 32; ++j) {
      int c = tid & 127;
      int w = (tid >> 7) + 2 * j;
      dst[w * 128 + c] = f2h(tile[c][w]);
    }
  } else {
    int idx = (bid - 512) * 256 + tid;        // 0..331775
    if (idx < 294912) {
      // Wl2 idx = (((kk*16+mt)*4+ks)*64+lane)*8+e : o=mt*16+(lane&15), c=ks*32+(lane>>4)*8+e
      int e = idx & 7, lane = (idx >> 3) & 63, ks = (idx >> 9) & 3;
      int mt = (idx >> 11) & 15, kk = idx >> 15;
      int o = mt * 16 + (lane & 15), c = ks * 32 + (lane >> 4) * 8 + e;
      Wl2[idx] = f2h(w_dc[(o * 128 + c) * 9 + kk]);
    } else {
      int i2 = idx - 294912;                  // 0..36863
      int e = i2 & 7, lane = (i2 >> 3) & 63, ks = (i2 >> 9) & 3;
      int mt = (i2 >> 11) & 1, kk = i2 >> 12;
      int co = mt * 16 + (lane & 15), c = ks * 32 + (lane >> 4) * 8 + e;
      Wol2[i2] = (co < 18) ? f2h(w_off[(co * 128 + c) * 9 + kk]) : (u16)0;
    }
  }
}

// ---------------- offset conv -> sampling table ----------------
__device__ __forceinline__ void make_entry(u32x4* __restrict__ tblG, int b, int kk,
                                           int ho, int wo, float offy, float offx) {
  int ki = kk / 3, kj = kk - ki * 3;
  float py = offy + (float)(ho + ki - 1);
  float px = offx + (float)(wo + kj - 1);
  float fy0 = floorf(py), fx0 = floorf(px);
  int y0 = (int)fy0, x0 = (int)fx0;
  float fy = py - fy0, fx = px - fx0;
  float w11 = fy * fx, w10 = fy - w11, w01 = fx - w11, w00 = 1.f - fy - fx + w11;
  bool iy0 = (y0 >= 0) & (y0 < 64), iy1 = (y0 >= -1) & (y0 < 63);
  bool ix0 = (x0 >= 0) & (x0 < 64), ix1 = (x0 >= -1) & (x0 < 63);
  int y0c = min(max(y0, 0), 63), x0c = min(max(x0, 0), 63);
  u32 addr00 = (u32)((y0c * 64 + x0c) * 128);
  u32 dx = (x0 >= 0 && x0 < 63) ? 128u : 0u;
  u32 dy = (y0 >= 0 && y0 < 63) ? 8192u : 0u;
  u32 wA = (u32)f2h((iy0 && ix0) ? w00 : 0.f) | ((u32)f2h((iy0 && ix1) ? w01 : 0.f) << 16);
  u32 wB = (u32)f2h((iy1 && ix0) ? w10 : 0.f) | ((u32)f2h((iy1 && ix1) ? w11 : 0.f) << 16);
  u32x4 ent; ent.x = addr00; ent.y = dx | (dy << 16); ent.z = wA; ent.w = wB;
  tblG[((size_t)(b * 9 + kk) << 12) + (ho << 6) + wo] = ent;
}

__global__ __launch_bounds__(512, 4) void offset_k(const u16* __restrict__ xh,
                                                   const u16* __restrict__ Wol2,
                                                   const float* __restrict__ b_off,
                                                   u32x4* __restrict__ tblG) {
  __shared__ u16 cols[2][64][128];
  int bid = blockIdx.x;
  int swz = (bid & 7) * 64 + (bid >> 3);
  int b = swz >> 6, ho = swz & 63;
  int tid = threadIdx.x, lane = tid & 63, wv = tid >> 6;
  int ln15 = lane & 15, kg = lane >> 4;
  int cl = (tid & 31) * 4;            // channel base, const per thread
  int l0 = tid >> 5;                  // 0..15
  const u16* xb = xh + (size_t)b * 524288;

  u32x2 sv[4];
  auto stage_issue = [&](int kn) {
    int ki = kn / 3, kj = kn - ki * 3;
    int hr = ho + ki - 1; hr = hr < 0 ? -hr : (hr > 63 ? 126 - hr : hr);
#pragma unroll
    for (int i = 0; i < 4; ++i) {
      int l = l0 + i * 16;
      int wr = l + kj - 1; wr = wr < 0 ? -wr : (wr > 63 ? 126 - wr : wr);
      sv[i] = *(const u32x2*)(xb + (hr * 64 + wr) * 128 + cl);
    }
  };
  auto stage_write = [&](int dbuf) {
    int swzc = cl ^ ((l0 & 7) << 3);
#pragma unroll
    for (int i = 0; i < 4; ++i) {
      *(u32x2*)&cols[dbuf][l0 + i * 16][swzc] = sv[i];
    }
  };

  int mt = wv & 1, ntq = wv >> 1;     // wave tile: co-half mt, l-quarter ntq
  int lq = ntq * 16 + ln15;
  f32x4 acc = {0.f, 0.f, 0.f, 0.f};

  stage_issue(0);
  stage_write(0);
  __syncthreads();
  for (int kk = 0; kk < 9; ++kk) {
    int buf = kk & 1;
    const u16* wb = Wol2 + ((kk * 2 + mt) * 4) * 512;
    short8 a0 = *(const short8*)(wb + 0 * 512 + lane * 8);
    short8 a1 = *(const short8*)(wb + 1 * 512 + lane * 8);
    short8 a2 = *(const short8*)(wb + 2 * 512 + lane * 8);
    short8 a3 = *(const short8*)(wb + 3 * 512 + lane * 8);
    if (kk < 8) stage_issue(kk + 1);
    int swzb = (lq & 7) << 3;
    acc = mfma16(a0, *(const short8*)&cols[buf][lq][(0 * 32 + kg * 8) ^ swzb], acc);
    acc = mfma16(a1, *(const short8*)&cols[buf][lq][(1 * 32 + kg * 8) ^ swzb], acc);
    acc = mfma16(a2, *(const short8*)&cols[buf][lq][(2 * 32 + kg * 8) ^ swzb], acc);
    acc = mfma16(a3, *(const short8*)&cols[buf][lq][(3 * 32 + kg * 8) ^ swzb], acc);
    if (kk < 8) stage_write(buf ^ 1);
    __syncthreads();
  }
  // epilogue: mt=0 -> channels kg*4..kg*4+3 = (y,x) of kk=2kg, 2kg+1
  //           mt=1 -> channels 16+kg*4.. -> only 16,17 valid (kk=8, kg=0)
  int wo = lq;
  if (mt == 0) {
    int kkA = 2 * kg, kkB = 2 * kg + 1;
    make_entry(tblG, b, kkA, ho, wo, acc[0] + b_off[2 * kkA], acc[1] + b_off[2 * kkA + 1]);
    make_entry(tblG, b, kkB, ho, wo, acc[2] + b_off[2 * kkB], acc[3] + b_off[2 * kkB + 1]);
  } else if (kg == 0) {
    make_entry(tblG, b, 8, ho, wo, acc[0] + b_off[16], acc[1] + b_off[17]);
  }
}

// ---------------- main: T14 split gather || MFMA, kk-sliced double buffer ----------------
__global__ __launch_bounds__(512, 4) void deform_main(
    const u16* __restrict__ xh, const u16* __restrict__ Wl2,
    const u32x4* __restrict__ tblG, const float* __restrict__ b_dc,
    float* __restrict__ out) {
  __shared__ u16 cols[2][64][128];     // 32768 B
  __shared__ u32x4 tbl[576];           //  9216 B
  int bid = blockIdx.x;
  int swz = (bid & 7) * 64 + (bid >> 3);
  int b = swz >> 6, ho = swz & 63;
  int tid = threadIdx.x, lane = tid & 63, wv = tid >> 6;
  int ln15 = lane & 15, kg = lane >> 4;
  int cl = (tid & 31) * 4;             // const per thread
  int l0 = tid >> 5;                   // 0..15
  const u16* xb = xh + (size_t)b * 524288;

  // stage sampling table: 576 entries, 512 threads
  {
    size_t base = (size_t)b * 9 * 4096 + ho * 64;
    tbl[tid] = tblG[base + (tid >> 6) * 4096 + (tid & 63)];
    if (tid < 64) tbl[512 + tid] = tblG[base + 8 * 4096 + tid];
  }
  __syncthreads();

  u32x2 gv[4][4];
  u32 gz[4], gw[4];
  auto gissue = [&](int g) {
#pragma unroll
    for (int i = 0; i < 4; ++i) {
      int l = l0 + i * 16;
      u32x4 e = tbl[g * 64 + l];
      const u16* p = xb + e.x + cl;
      u32 dxv = e.y & 0xffffu, dyv = e.y >> 16;
      gv[i][0] = *(const u32x2*)p;
      gv[i][1] = *(const u32x2*)(p + dxv);
      gv[i][2] = *(const u32x2*)(p + dyv);
      gv[i][3] = *(const u32x2*)(p + dyv + dxv);
      gz[i] = e.z; gw[i] = e.w;
    }
  };
  auto gwrite = [&](int dbuf) {
    int swzc = cl ^ ((l0 & 7) << 3);
#pragma unroll
    for (int i = 0; i < 4; ++i) {
      __half2 wA = h2cast(gz[i]), wB = h2cast(gw[i]);
      __half2 w00 = __half2half2(wA.x), w01 = __half2half2(wA.y);
      __half2 w10 = __half2half2(wB.x), w11 = __half2half2(wB.y);
      __half2 r0 = __hmul2(h2cast(gv[i][0][0]), w00);
      r0 = __hfma2(h2cast(gv[i][1][0]), w01, r0);
      r0 = __hfma2(h2cast(gv[i][2][0]), w10, r0);
      r0 = __hfma2(h2cast(gv[i][3][0]), w11, r0);
      __half2 r1 = __hmul2(h2cast(gv[i][0][1]), w00);
      r1 = __hfma2(h2cast(gv[i][1][1]), w01, r1);
      r1 = __hfma2(h2cast(gv[i][2][1]), w10, r1);
      r1 = __hfma2(h2cast(gv[i][3][1]), w11, r1);
      u32x2 pv;
      pv[0] = __builtin_bit_cast(u32, r0);
      pv[1] = __builtin_bit_cast(u32, r1);
      *(u32x2*)&cols[dbuf][l0 + i * 16][swzc] = pv;
    }
  };

  f32x4 acc[2][4];
#pragma unroll
  for (int m = 0; m < 2; ++m)
#pragma unroll
    for (int n = 0; n < 4; ++n) acc[m][n] = (f32x4){0.f, 0.f, 0.f, 0.f};

  // prologue: gather tile 0
  gissue(0);
  gwrite(0);
  __syncthreads();

  for (int kk = 0; kk < 9; ++kk) {
    int buf = kk & 1;
    // (1) A-fragment loads for kk, issued FIRST (vmcnt wait won't drain gathers)
    const u16* wbase = Wl2 + (size_t)((kk * 16 + wv * 2) * 4) * 512;
    short8 a[8];
#pragma unroll
    for (int ks = 0; ks < 4; ++ks) {
      a[ks]     = *(const short8*)(wbase + ks * 512 + lane * 8);
      a[4 + ks] = *(const short8*)(wbase + (4 + ks) * 512 + lane * 8);
    }
    // (2) issue next gather loads -> regs
    if (kk < 8) gissue(kk + 1);
    // (3) MFMA on current buffer (ds_reads not blocked by gather ds_writes)
#pragma unroll
    for (int ks = 0; ks < 4; ++ks) {
#pragma unroll
      for (int nt = 0; nt < 4; ++nt) {
        int l = nt * 16 + ln15;
        short8 bfv = *(const short8*)&cols[buf][l][(ks * 32 + kg * 8) ^ ((l & 7) << 3)];
        acc[0][nt] = mfma16(a[ks], bfv, acc[0][nt]);
        acc[1][nt] = mfma16(a[4 + ks], bfv, acc[1][nt]);
      }
    }
    // (4) combine + write next buffer
    if (kk < 8) gwrite(buf ^ 1);
    __syncthreads();
  }

  // epilogue
#pragma unroll
  for (int mt = 0; mt < 2; ++mt) {
#pragma unroll
    for (int r = 0; r < 4; ++r) {
      int o = wv * 32 + mt * 16 + kg * 4 + r;
      float bias = b_dc[o];
      size_t base = ((size_t)(b * 256 + o)) * 4096 + ho * 64;
#pragma unroll
      for (int nt = 0; nt < 4; ++nt) {
        out[base + nt * 16 + ln15] = acc[mt][nt][r] + bias;
      }
    }
  }
}

extern "C" void kernel_launch(void* const* d_in, const int* in_sizes, int n_in,
                              void* d_out, int out_size, void* d_ws, size_t ws_size,
                              hipStream_t stream) {
  const float* x     = (const float*)d_in[0];
  const float* w_off = (const float*)d_in[1];
  const float* b_off = (const float*)d_in[2];
  const float* w_dc  = (const float*)d_in[3];
  const float* b_dc  = (const float*)d_in[4];
  float* out = (float*)d_out;
  char* ws = (char*)d_ws;
  u16*   xh   = (u16*)ws;                                   // 8,388,608 B
  u16*   Wl2  = (u16*)(ws + 8388608);                       //   589,824 B
  u16*   Wol2 = (u16*)(ws + 8388608 + 589824);              //    73,728 B
  u32x4* tblG = (u32x4*)(ws + 9052160);                     // 4,718,592 B (tot 13.8 MB)
  prep_fused<<<dim3(1808), dim3(256), 0, stream>>>(x, w_dc, w_off, xh, Wl2, Wol2);
  offset_k  <<<dim3(512),  dim3(512), 0, stream>>>(xh, Wol2, b_off, tblG);
  deform_main<<<dim3(512), dim3(512), 0, stream>>>(xh, Wl2, tblG, b_dc, out);
}

// Round 5
// 48.963 us; speedup vs baseline: 2.9186x; 1.1958x over previous
//
#include <hip/hip_runtime.h>
#include <hip/hip_fp16.h>

typedef unsigned short u16;
typedef unsigned int   u32;
typedef u32   u32x2  __attribute__((ext_vector_type(2)));
typedef u32   u32x4  __attribute__((ext_vector_type(4)));
typedef short short8 __attribute__((ext_vector_type(8)));
typedef float f32x4  __attribute__((ext_vector_type(4)));
typedef _Float16 half8 __attribute__((ext_vector_type(8)));

__device__ __forceinline__ u16 f2h(float f) { return __half_as_ushort(__float2half(f)); }
__device__ __forceinline__ f32x4 mfma16(short8 a, short8 b, f32x4 c) {
  return __builtin_amdgcn_mfma_f32_16x16x32_f16(
      __builtin_bit_cast(half8, a), __builtin_bit_cast(half8, b), c, 0, 0, 0);
}
__device__ __forceinline__ __half2 h2cast(u32 u) { return __builtin_bit_cast(__half2, u); }

// ---------------- fused prep: x NCHW f32 -> NHWC f16 ; weights -> MFMA order ----------------
__global__ __launch_bounds__(256) void prep_fused(const float* __restrict__ x,
                                                  const float* __restrict__ w_dc,
                                                  const float* __restrict__ w_off,
                                                  u16* __restrict__ xh,
                                                  u16* __restrict__ Wl2,
                                                  u16* __restrict__ Wol2) {
  int bid = blockIdx.x;
  int tid = threadIdx.x;
  if (bid < 512) {
    __shared__ float tile[128][65];
    int swz = (bid & 7) * 64 + (bid >> 3);
    int b = swz >> 6, h = swz & 63;
    for (int i = 0; i < 32; ++i) {
      int c = (tid >> 6) + i * 4;
      int w = tid & 63;
      tile[c][w] = x[(((size_t)b * 128 + c) * 64 + h) * 64 + w];
    }
    __syncthreads();
    u16* dst = xh + ((size_t)(b * 64 + h) * 64) * 128;
    for (int j = 0; j < 32; ++j) {
      int c = tid & 127;
      int w = (tid >> 7) + 2 * j;
      dst[w * 128 + c] = f2h(tile[c][w]);
    }
  } else {
    int idx = (bid - 512) * 256 + tid;        // 0..331775
    if (idx < 294912) {
      // Wl2 idx = (((kk*16+mt)*4+ks)*64+lane)*8+e : o=mt*16+(lane&15), c=ks*32+(lane>>4)*8+e
      int e = idx & 7, lane = (idx >> 3) & 63, ks = (idx >> 9) & 3;
      int mt = (idx >> 11) & 15, kk = idx >> 15;
      int o = mt * 16 + (lane & 15), c = ks * 32 + (lane >> 4) * 8 + e;
      Wl2[idx] = f2h(w_dc[(o * 128 + c) * 9 + kk]);
    } else {
      int i2 = idx - 294912;                  // 0..36863
      int e = i2 & 7, lane = (i2 >> 3) & 63, ks = (i2 >> 9) & 3;
      int mt = (i2 >> 11) & 1, kk = i2 >> 12;
      int co = mt * 16 + (lane & 15), c = ks * 32 + (lane >> 4) * 8 + e;
      Wol2[i2] = (co < 18) ? f2h(w_off[(co * 128 + c) * 9 + kk]) : (u16)0;
    }
  }
}

// ---------------- sampling-table entry (written to LDS) ----------------
__device__ __forceinline__ void make_entry_lds(u32x4* __restrict__ tbl, int kk,
                                               int ho, int wo, float offy, float offx) {
  int ki = kk / 3, kj = kk - ki * 3;
  float py = offy + (float)(ho + ki - 1);
  float px = offx + (float)(wo + kj - 1);
  float fy0 = floorf(py), fx0 = floorf(px);
  int y0 = (int)fy0, x0 = (int)fx0;
  float fy = py - fy0, fx = px - fx0;
  float w11 = fy * fx, w10 = fy - w11, w01 = fx - w11, w00 = 1.f - fy - fx + w11;
  bool iy0 = (y0 >= 0) & (y0 < 64), iy1 = (y0 >= -1) & (y0 < 63);
  bool ix0 = (x0 >= 0) & (x0 < 64), ix1 = (x0 >= -1) & (x0 < 63);
  int y0c = min(max(y0, 0), 63), x0c = min(max(x0, 0), 63);
  u32 addr00 = (u32)((y0c * 64 + x0c) * 128);          // u16-element offset
  u32 dx = (x0 >= 0 && x0 < 63) ? 128u : 0u;
  u32 dy = (y0 >= 0 && y0 < 63) ? 8192u : 0u;
  u32 wA = (u32)f2h((iy0 && ix0) ? w00 : 0.f) | ((u32)f2h((iy0 && ix1) ? w01 : 0.f) << 16);
  u32 wB = (u32)f2h((iy1 && ix0) ? w10 : 0.f) | ((u32)f2h((iy1 && ix1) ? w11 : 0.f) << 16);
  u32x4 ent; ent.x = addr00; ent.y = dx | (dy << 16); ent.z = wA; ent.w = wB;
  tbl[kk * 64 + wo] = ent;
}

// ---------------- fused: offset conv -> table -> gather || MFMA main GEMM ----------------
__global__ __launch_bounds__(512, 4) void deform_fused(
    const u16* __restrict__ xh, const u16* __restrict__ Wl2,
    const u16* __restrict__ Wol2, const float* __restrict__ b_off,
    const float* __restrict__ b_dc, float* __restrict__ out) {
  __shared__ u16 cols[2][64][128];     // 32768 B
  __shared__ u32x4 tbl[576];           //  9216 B
  int bid = blockIdx.x;
  int swz = (bid & 7) * 64 + (bid >> 3);   // XCD -> batch
  int b = swz >> 6, ho = swz & 63;
  int tid = threadIdx.x, lane = tid & 63, wv = tid >> 6;
  int ln15 = lane & 15, kg = lane >> 4;
  const u16* xb = xh + (size_t)b * 524288;

  // task geometry (staging & gather): task T = tid + i*512 -> l = T>>4, c-base = (T&15)*8
  int tl0 = tid >> 4;                  // l for i=0 (0..31); i=1 adds 32
  int tcl = (tid & 15) * 8;            // channel base (8 ch, 16B)
  int swzc = tcl ^ ((tl0 & 7) << 3);   // (tl0+32)&7 == tl0&7, so same for both tasks

  // ================= phase A: offset conv =================
  u32x4 sv[2];
  auto stage_issue = [&](int kn) {
    int ki = kn / 3, kj = kn - ki * 3;
    int hr = ho + ki - 1; hr = hr < 0 ? -hr : (hr > 63 ? 126 - hr : hr);
#pragma unroll
    for (int i = 0; i < 2; ++i) {
      int l = tl0 + i * 32;
      int wr = l + kj - 1; wr = wr < 0 ? -wr : (wr > 63 ? 126 - wr : wr);
      sv[i] = *(const u32x4*)(xb + (hr * 64 + wr) * 128 + tcl);
    }
  };
  auto stage_write = [&](int dbuf) {
    *(u32x4*)&cols[dbuf][tl0][swzc]      = sv[0];
    *(u32x4*)&cols[dbuf][tl0 + 32][swzc] = sv[1];
  };

  int mt = wv & 1, ntq = wv >> 1;      // wave tile: co-half mt, l-quarter ntq
  int lq = ntq * 16 + ln15;
  int swzb = (lq & 7) << 3;
  f32x4 oacc = {0.f, 0.f, 0.f, 0.f};

  stage_issue(0);
  stage_write(0);
  __syncthreads();
  for (int kk = 0; kk < 9; ++kk) {
    int buf = kk & 1;
    const u16* wb = Wol2 + ((kk * 2 + mt) * 4) * 512 + lane * 8;
    short8 a0 = *(const short8*)(wb);
    short8 a1 = *(const short8*)(wb + 512);
    short8 a2 = *(const short8*)(wb + 1024);
    short8 a3 = *(const short8*)(wb + 1536);
    if (kk < 8) stage_issue(kk + 1);
    oacc = mfma16(a0, *(const short8*)&cols[buf][lq][(0 * 32 + kg * 8) ^ swzb], oacc);
    oacc = mfma16(a1, *(const short8*)&cols[buf][lq][(1 * 32 + kg * 8) ^ swzb], oacc);
    oacc = mfma16(a2, *(const short8*)&cols[buf][lq][(2 * 32 + kg * 8) ^ swzb], oacc);
    oacc = mfma16(a3, *(const short8*)&cols[buf][lq][(3 * 32 + kg * 8) ^ swzb], oacc);
    if (kk < 8) stage_write(buf ^ 1);
    __syncthreads();
  }
  // epilogue -> LDS table. mt=0: co=kg*4+r -> (dy,dx) of kk=2kg,2kg+1 ; mt=1,kg=0: kk=8
  {
    int wo = lq;
    if (mt == 0) {
      int kkA = 2 * kg, kkB = 2 * kg + 1;
      make_entry_lds(tbl, kkA, ho, wo, oacc[0] + b_off[2 * kkA], oacc[1] + b_off[2 * kkA + 1]);
      make_entry_lds(tbl, kkB, ho, wo, oacc[2] + b_off[2 * kkB], oacc[3] + b_off[2 * kkB + 1]);
    } else if (kg == 0) {
      make_entry_lds(tbl, 8, ho, wo, oacc[0] + b_off[16], oacc[1] + b_off[17]);
    }
  }
  __syncthreads();

  // ================= phase B: deformable GEMM =================
  u32x4 gv[2][4];
  u32x4 ge[2];
  auto gissue = [&](int g) {
#pragma unroll
    for (int i = 0; i < 2; ++i) {
      int l = tl0 + i * 32;
      u32x4 e = tbl[g * 64 + l];
      ge[i] = e;
      const u16* p = xb + e.x + tcl;
      u32 dxv = e.y & 0xffffu, dyv = e.y >> 16;
      gv[i][0] = *(const u32x4*)p;
      gv[i][1] = *(const u32x4*)(p + dxv);
      gv[i][2] = *(const u32x4*)(p + dyv);
      gv[i][3] = *(const u32x4*)(p + dyv + dxv);
    }
  };
  auto gwrite = [&](int dbuf) {
#pragma unroll
    for (int i = 0; i < 2; ++i) {
      __half2 wA = h2cast(ge[i].z), wB = h2cast(ge[i].w);
      __half2 w00 = __half2half2(wA.x), w01 = __half2half2(wA.y);
      __half2 w10 = __half2half2(wB.x), w11 = __half2half2(wB.y);
      u32x4 pv;
#pragma unroll
      for (int wd = 0; wd < 4; ++wd) {
        __half2 r = __hmul2(h2cast(gv[i][0][wd]), w00);
        r = __hfma2(h2cast(gv[i][1][wd]), w01, r);
        r = __hfma2(h2cast(gv[i][2][wd]), w10, r);
        r = __hfma2(h2cast(gv[i][3][wd]), w11, r);
        pv[wd] = __builtin_bit_cast(u32, r);
      }
      *(u32x4*)&cols[dbuf][tl0 + i * 32][swzc] = pv;
    }
  };

  f32x4 acc[2][4];
#pragma unroll
  for (int m = 0; m < 2; ++m)
#pragma unroll
    for (int n = 0; n < 4; ++n) acc[m][n] = (f32x4){0.f, 0.f, 0.f, 0.f};

  gissue(0);
  gwrite(0);
  __syncthreads();

  for (int kk = 0; kk < 9; ++kk) {
    int buf = kk & 1;
    // (1) A-fragment loads for kk, issued FIRST (their vmcnt wait won't drain gathers)
    const u16* wbase = Wl2 + (size_t)((kk * 16 + wv * 2) * 4) * 512;
    short8 a[8];
#pragma unroll
    for (int ks = 0; ks < 4; ++ks) {
      a[ks]     = *(const short8*)(wbase + ks * 512 + lane * 8);
      a[4 + ks] = *(const short8*)(wbase + (4 + ks) * 512 + lane * 8);
    }
    // (2) issue next gather loads -> regs
    if (kk < 8) gissue(kk + 1);
    // (3) MFMA on current buffer
#pragma unroll
    for (int ks = 0; ks < 4; ++ks) {
#pragma unroll
      for (int nt = 0; nt < 4; ++nt) {
        int l = nt * 16 + ln15;
        short8 bfv = *(const short8*)&cols[buf][l][(ks * 32 + kg * 8) ^ ((l & 7) << 3)];
        acc[0][nt] = mfma16(a[ks], bfv, acc[0][nt]);
        acc[1][nt] = mfma16(a[4 + ks], bfv, acc[1][nt]);
      }
    }
    // (4) combine + write next buffer
    if (kk < 8) gwrite(buf ^ 1);
    __syncthreads();
  }

  // epilogue
#pragma unroll
  for (int mtt = 0; mtt < 2; ++mtt) {
#pragma unroll
    for (int r = 0; r < 4; ++r) {
      int o = wv * 32 + mtt * 16 + kg * 4 + r;
      float bias = b_dc[o];
      size_t base = ((size_t)(b * 256 + o)) * 4096 + ho * 64;
#pragma unroll
      for (int nt = 0; nt < 4; ++nt) {
        out[base + nt * 16 + ln15] = acc[mtt][nt][r] + bias;
      }
    }
  }
}

extern "C" void kernel_launch(void* const* d_in, const int* in_sizes, int n_in,
                              void* d_out, int out_size, void* d_ws, size_t ws_size,
                              hipStream_t stream) {
  const float* x     = (const float*)d_in[0];
  const float* w_off = (const float*)d_in[1];
  const float* b_off = (const float*)d_in[2];
  const float* w_dc  = (const float*)d_in[3];
  const float* b_dc  = (const float*)d_in[4];
  float* out = (float*)d_out;
  char* ws = (char*)d_ws;
  u16* xh   = (u16*)ws;                                   // 8,388,608 B
  u16* Wl2  = (u16*)(ws + 8388608);                       //   589,824 B
  u16* Wol2 = (u16*)(ws + 8388608 + 589824);              //    73,728 B (tot 9.05 MB)
  prep_fused  <<<dim3(1808), dim3(256), 0, stream>>>(x, w_dc, w_off, xh, Wl2, Wol2);
  deform_fused<<<dim3(512),  dim3(512), 0, stream>>>(xh, Wl2, Wol2, b_off, b_dc, out);
}

// Round 6
// 47.610 us; speedup vs baseline: 3.0016x; 1.0284x over previous
//
#include <hip/hip_runtime.h>
#include <hip/hip_fp16.h>

typedef unsigned short u16;
typedef unsigned int   u32;
typedef u32   u32x2  __attribute__((ext_vector_type(2)));
typedef u32   u32x4  __attribute__((ext_vector_type(4)));
typedef short short8 __attribute__((ext_vector_type(8)));
typedef float f32x4  __attribute__((ext_vector_type(4)));
typedef _Float16 half8 __attribute__((ext_vector_type(8)));

__device__ __forceinline__ u16 f2h(float f) { return __half_as_ushort(__float2half(f)); }
__device__ __forceinline__ f32x4 mfma16(short8 a, short8 b, f32x4 c) {
  return __builtin_amdgcn_mfma_f32_16x16x32_f16(
      __builtin_bit_cast(half8, a), __builtin_bit_cast(half8, b), c, 0, 0, 0);
}
__device__ __forceinline__ __half2 h2cast(u32 u) { return __builtin_bit_cast(__half2, u); }

// ---------------- fused prep: x NCHW f32 -> NHWC f16 ; weights -> MFMA order ----------------
__global__ __launch_bounds__(256) void prep_fused(const float* __restrict__ x,
                                                  const float* __restrict__ w_dc,
                                                  const float* __restrict__ w_off,
                                                  u16* __restrict__ xh,
                                                  u16* __restrict__ Wl2,
                                                  u16* __restrict__ Wol2) {
  int bid = blockIdx.x;
  int tid = threadIdx.x;
  if (bid < 512) {
    __shared__ float tile[128][65];
    int swz = (bid & 7) * 64 + (bid >> 3);
    int b = swz >> 6, h = swz & 63;
    for (int i = 0; i < 32; ++i) {
      int c = (tid >> 6) + i * 4;
      int w = tid & 63;
      tile[c][w] = x[(((size_t)b * 128 + c) * 64 + h) * 64 + w];
    }
    __syncthreads();
    u16* dst = xh + ((size_t)(b * 64 + h) * 64) * 128;
    for (int j = 0; j < 32; ++j) {
      int c = tid & 127;
      int w = (tid >> 7) + 2 * j;
      dst[w * 128 + c] = f2h(tile[c][w]);
    }
  } else {
    int idx = (bid - 512) * 256 + tid;        // 0..331775
    if (idx < 294912) {
      // Wl2 idx = (((kk*16+mt)*4+ks)*64+lane)*8+e : o=mt*16+(lane&15), c=ks*32+(lane>>4)*8+e
      int e = idx & 7, lane = (idx >> 3) & 63, ks = (idx >> 9) & 3;
      int mt = (idx >> 11) & 15, kk = idx >> 15;
      int o = mt * 16 + (lane & 15), c = ks * 32 + (lane >> 4) * 8 + e;
      Wl2[idx] = f2h(w_dc[(o * 128 + c) * 9 + kk]);
    } else {
      int i2 = idx - 294912;                  // 0..36863
      int e = i2 & 7, lane = (i2 >> 3) & 63, ks = (i2 >> 9) & 3;
      int mt = (i2 >> 11) & 1, kk = i2 >> 12;
      int co = mt * 16 + (lane & 15), c = ks * 32 + (lane >> 4) * 8 + e;
      Wol2[i2] = (co < 18) ? f2h(w_off[(co * 128 + c) * 9 + kk]) : (u16)0;
    }
  }
}

// ---------------- sampling-table entry (written to LDS) ----------------
__device__ __forceinline__ void make_entry_lds(u32x4* __restrict__ tbl, int kk,
                                               int ho, int wo, float offy, float offx) {
  int ki = kk / 3, kj = kk - ki * 3;
  float py = offy + (float)(ho + ki - 1);
  float px = offx + (float)(wo + kj - 1);
  float fy0 = floorf(py), fx0 = floorf(px);
  int y0 = (int)fy0, x0 = (int)fx0;
  float fy = py - fy0, fx = px - fx0;
  float w11 = fy * fx, w10 = fy - w11, w01 = fx - w11, w00 = 1.f - fy - fx + w11;
  bool iy0 = (y0 >= 0) & (y0 < 64), iy1 = (y0 >= -1) & (y0 < 63);
  bool ix0 = (x0 >= 0) & (x0 < 64), ix1 = (x0 >= -1) & (x0 < 63);
  int y0c = min(max(y0, 0), 63), x0c = min(max(x0, 0), 63);
  u32 addr00 = (u32)((y0c * 64 + x0c) * 128);          // u16-element offset
  u32 dx = (x0 >= 0 && x0 < 63) ? 128u : 0u;
  u32 dy = (y0 >= 0 && y0 < 63) ? 8192u : 0u;
  u32 wA = (u32)f2h((iy0 && ix0) ? w00 : 0.f) | ((u32)f2h((iy0 && ix1) ? w01 : 0.f) << 16);
  u32 wB = (u32)f2h((iy1 && ix0) ? w10 : 0.f) | ((u32)f2h((iy1 && ix1) ? w11 : 0.f) << 16);
  u32x4 ent; ent.x = addr00; ent.y = dx | (dy << 16); ent.z = wA; ent.w = wB;
  tbl[kk * 64 + wo] = ent;
}

// ---------------- fused: offset conv (slab) -> table -> gather || MFMA GEMM ----------------
__global__ __launch_bounds__(512, 4) void deform_fused(
    const u16* __restrict__ xh, const u16* __restrict__ Wl2,
    const u16* __restrict__ Wol2, const float* __restrict__ b_off,
    const float* __restrict__ b_dc, float* __restrict__ out) {
  union SMU {
    u16 slab[3][64][128];                           // 49152 B (phase A)
    struct { u16 cols[2][64][128]; u32x4 tbl[576]; } pb;  // 32768 + 9216 (phase B; tbl aliases slab[2])
  };
  __shared__ SMU sm;
  int bid = blockIdx.x;
  int swz = (bid & 7) * 64 + (bid >> 3);   // XCD -> batch
  int b = swz >> 6, ho = swz & 63;
  int tid = threadIdx.x, lane = tid & 63, wv = tid >> 6;
  int ln15 = lane & 15, kg = lane >> 4;
  const u16* xb = xh + (size_t)b * 524288;

  // task geometry (gather/stage): task T = tid + i*512 -> l = T>>4, c-base = (T&15)*8
  int tl0 = tid >> 4;                  // 0..31 ; +32 for i=1
  int tcl = (tid & 15) * 8;            // channel base (8 ch, 16B)
  int swzc = tcl ^ ((tl0 & 7) << 3);

  // ================= phase A: stage 3-row slab once =================
  {
    u32x4 st[6];
#pragma unroll
    for (int i = 0; i < 6; ++i) {
      int T = tid + i * 512;
      int r = T >> 10, w = (T >> 4) & 63, cb = (T & 15) * 8;
      int hr = ho + r - 1; hr = hr < 0 ? -hr : (hr > 63 ? 126 - hr : hr);
      st[i] = *(const u32x4*)(xb + (hr * 64 + w) * 128 + cb);
    }
#pragma unroll
    for (int i = 0; i < 6; ++i) {
      int T = tid + i * 512;
      int r = T >> 10, w = (T >> 4) & 63, cb = (T & 15) * 8;
      *(u32x4*)&sm.slab[r][w][cb ^ ((w & 7) << 3)] = st[i];
    }
  }
  __syncthreads();

  // ---- offset conv: 36 MFMA burst, no barriers (slab read-only) ----
  int mt = wv & 1, ntq = wv >> 1;
  int lq = ntq * 16 + ln15;
  f32x4 oacc = {0.f, 0.f, 0.f, 0.f};
  __builtin_amdgcn_s_setprio(1);
#pragma unroll
  for (int kk = 0; kk < 9; ++kk) {
    int ki = kk / 3, kj = kk - ki * 3;
    int wr = lq + kj - 1; wr = wr < 0 ? -wr : (wr > 63 ? 126 - wr : wr);
    const u16* wb = Wol2 + ((kk * 2 + mt) * 4) * 512 + lane * 8;
    int sb = (wr & 7) << 3;
#pragma unroll
    for (int ks = 0; ks < 4; ++ks) {
      short8 af = *(const short8*)(wb + ks * 512);
      short8 bf = *(const short8*)&sm.slab[ki][wr][(ks * 32 + kg * 8) ^ sb];
      oacc = mfma16(af, bf, oacc);
    }
  }
  __builtin_amdgcn_s_setprio(0);
  __syncthreads();                       // all slab reads done (tbl aliases slab[2])

  // ---- write sampling table ----
  {
    int wo = lq;
    if (mt == 0) {
      int kkA = 2 * kg, kkB = 2 * kg + 1;
      make_entry_lds(sm.pb.tbl, kkA, ho, wo, oacc[0] + b_off[2 * kkA], oacc[1] + b_off[2 * kkA + 1]);
      make_entry_lds(sm.pb.tbl, kkB, ho, wo, oacc[2] + b_off[2 * kkB], oacc[3] + b_off[2 * kkB + 1]);
    } else if (kg == 0) {
      make_entry_lds(sm.pb.tbl, 8, ho, wo, oacc[0] + b_off[16], oacc[1] + b_off[17]);
    }
  }
  __syncthreads();                       // tbl visible

  // ================= phase B: deformable GEMM =================
  u32x4 gv[2][4];
  u32x4 ge[2];
  auto gissue = [&](int g) {
#pragma unroll
    for (int i = 0; i < 2; ++i) {
      int l = tl0 + i * 32;
      u32x4 e = sm.pb.tbl[g * 64 + l];
      ge[i] = e;
      const u16* p = xb + e.x + tcl;
      u32 dxv = e.y & 0xffffu, dyv = e.y >> 16;
      gv[i][0] = *(const u32x4*)p;
      gv[i][1] = *(const u32x4*)(p + dxv);
      gv[i][2] = *(const u32x4*)(p + dyv);
      gv[i][3] = *(const u32x4*)(p + dyv + dxv);
    }
  };
  auto gwrite = [&](int dbuf) {
#pragma unroll
    for (int i = 0; i < 2; ++i) {
      __half2 wA = h2cast(ge[i].z), wB = h2cast(ge[i].w);
      __half2 w00 = __half2half2(wA.x), w01 = __half2half2(wA.y);
      __half2 w10 = __half2half2(wB.x), w11 = __half2half2(wB.y);
      u32x4 pv;
#pragma unroll
      for (int wd = 0; wd < 4; ++wd) {
        __half2 r = __hmul2(h2cast(gv[i][0][wd]), w00);
        r = __hfma2(h2cast(gv[i][1][wd]), w01, r);
        r = __hfma2(h2cast(gv[i][2][wd]), w10, r);
        r = __hfma2(h2cast(gv[i][3][wd]), w11, r);
        pv[wd] = __builtin_bit_cast(u32, r);
      }
      *(u32x4*)&sm.pb.cols[dbuf][tl0 + i * 32][swzc] = pv;
    }
  };

  f32x4 acc[2][4];
#pragma unroll
  for (int m = 0; m < 2; ++m)
#pragma unroll
    for (int n = 0; n < 4; ++n) acc[m][n] = (f32x4){0.f, 0.f, 0.f, 0.f};

  gissue(0);
  gwrite(0);
  __syncthreads();

  for (int kk = 0; kk < 9; ++kk) {
    int buf = kk & 1;
    // (1) A-fragment loads for kk, issued FIRST (their vmcnt wait won't drain gathers)
    const u16* wbase = Wl2 + (size_t)((kk * 16 + wv * 2) * 4) * 512;
    short8 a[8];
#pragma unroll
    for (int ks = 0; ks < 4; ++ks) {
      a[ks]     = *(const short8*)(wbase + ks * 512 + lane * 8);
      a[4 + ks] = *(const short8*)(wbase + (4 + ks) * 512 + lane * 8);
    }
    // (2) issue next gather loads -> regs
    if (kk < 8) gissue(kk + 1);
    // (3) MFMA on current buffer
    __builtin_amdgcn_s_setprio(1);
#pragma unroll
    for (int ks = 0; ks < 4; ++ks) {
#pragma unroll
      for (int nt = 0; nt < 4; ++nt) {
        int l = nt * 16 + ln15;
        short8 bfv = *(const short8*)&sm.pb.cols[buf][l][(ks * 32 + kg * 8) ^ ((l & 7) << 3)];
        acc[0][nt] = mfma16(a[ks], bfv, acc[0][nt]);
        acc[1][nt] = mfma16(a[4 + ks], bfv, acc[1][nt]);
      }
    }
    __builtin_amdgcn_s_setprio(0);
    // (4) combine + write next buffer
    if (kk < 8) gwrite(buf ^ 1);
    __syncthreads();
  }

  // epilogue
#pragma unroll
  for (int mtt = 0; mtt < 2; ++mtt) {
#pragma unroll
    for (int r = 0; r < 4; ++r) {
      int o = wv * 32 + mtt * 16 + kg * 4 + r;
      float bias = b_dc[o];
      size_t base = ((size_t)(b * 256 + o)) * 4096 + ho * 64;
#pragma unroll
      for (int nt = 0; nt < 4; ++nt) {
        out[base + nt * 16 + ln15] = acc[mtt][nt][r] + bias;
      }
    }
  }
}

extern "C" void kernel_launch(void* const* d_in, const int* in_sizes, int n_in,
                              void* d_out, int out_size, void* d_ws, size_t ws_size,
                              hipStream_t stream) {
  const float* x     = (const float*)d_in[0];
  const float* w_off = (const float*)d_in[1];
  const float* b_off = (const float*)d_in[2];
  const float* w_dc  = (const float*)d_in[3];
  const float* b_dc  = (const float*)d_in[4];
  float* out = (float*)d_out;
  char* ws = (char*)d_ws;
  u16* xh   = (u16*)ws;                                   // 8,388,608 B
  u16* Wl2  = (u16*)(ws + 8388608);                       //   589,824 B
  u16* Wol2 = (u16*)(ws + 8388608 + 589824);              //    73,728 B (tot 9.05 MB)
  prep_fused  <<<dim3(1808), dim3(256), 0, stream>>>(x, w_dc, w_off, xh, Wl2, Wol2);
  deform_fused<<<dim3(512),  dim3(512), 0, stream>>>(xh, Wl2, Wol2, b_off, b_dc, out);
}